// Round 4
// baseline (115.943 us; speedup 1.0000x reference)
//
#include <hip/hip_runtime.h>

#define IMG 28
#define FLATK 784     // 28*28
#define OHW 26
#define FLAT 676      // 26*26
#define HID 100
#define NCLS 10
#define KP 832        // K padded to 13*64
#define NSTEPS 13     // K-steps of 64
#define BM 64         // rows per block (4 waves x 16 rows)

typedef __attribute__((ext_vector_type(8))) short bfrag;   // 8 bf16 (4 VGPR)
typedef __attribute__((ext_vector_type(4))) float f32x4;
typedef __attribute__((ext_vector_type(4))) unsigned int u32x4;

__device__ __forceinline__ unsigned short f2bf(float f) {
    unsigned u = __float_as_uint(f);
    u = (u + 0x7fffu + ((u >> 16) & 1u)) >> 16;   // RNE
    return (unsigned short)u;
}

// Kernel 1: fold conv into fc1 -> bf16 W1eff [128 n][832 k] (zero-padded),
// and w2 -> bf16 [16 n][128 k] (zero-padded).
__global__ void build_weights(const float* __restrict__ conv_w,
                              const float* __restrict__ w1,
                              const float* __restrict__ w2,
                              unsigned short* __restrict__ w1b,
                              unsigned short* __restrict__ w2b) {
    int idx = blockIdx.x * blockDim.x + threadIdx.x;
    if (idx < 128 * KP) {
        int n = idx / KP, k = idx - n * KP;
        float val = 0.f;
        if (n < HID && k < FLATK) {
            int qr = k / IMG, qc = k % IMG;
            #pragma unroll
            for (int i = 0; i < 3; ++i) {
                int r = qr - i;
                if (r < 0 || r >= OHW) continue;
                #pragma unroll
                for (int j = 0; j < 3; ++j) {
                    int c = qc - j;
                    if (c < 0 || c >= OHW) continue;
                    val += conv_w[i * 3 + j] * w1[n * FLAT + r * OHW + c];
                }
            }
        }
        w1b[idx] = f2bf(val);
    } else {
        int t = idx - 128 * KP;
        if (t < 16 * 128) {
            int n = t >> 7, k = t & 127;
            float v = (n < NCLS && k < HID) ? w2[n * HID + k] : 0.f;
            w2b[t] = f2bf(v);
        }
    }
}

// Kernel 2: barrier-free main loop. Each wave owns 16 rows; A-fragments are
// loaded directly global->reg (depth-3 ring, 2 steps in flight), converted
// with v_cvt_pk_bf16_f32 at consume time; B-fragments read from L2-hot w1b.
// LDS used only for the h1 transpose between the two GEMMs.
__global__ __launch_bounds__(256, 4) void fused_fwd(
    const float* __restrict__ x,              // [65536][784] f32
    const unsigned short* __restrict__ w1b,   // [128][832] bf16
    const float* __restrict__ b1,             // [100]
    const unsigned short* __restrict__ w2b,   // [16][128] bf16
    const float* __restrict__ b2,             // [10]
    float* __restrict__ out)                  // [65536][10] f32
{
    __shared__ unsigned short H1[BM][136];    // 17408 B -> 4 blocks/CU fits

    const int tid  = threadIdx.x;
    const int lane = tid & 63;
    const int wv   = tid >> 6;
    const int row0 = blockIdx.x * BM;

    // A-fragment geometry: lane holds row (lane&15) of the wave's 16-row
    // slab, k-slice (lane>>4)*8 .. +8 (matches mfma 16x16x32 A layout).
    const int ksl = (lane >> 4) << 3;                  // 0,8,16,24
    const float* xr = x + (size_t)(row0 + (wv << 4) + (lane & 15)) * FLATK;

    f32x4 acc[8];
    #pragma unroll
    for (int n = 0; n < 8; ++n) acc[n] = f32x4{0.f, 0.f, 0.f, 0.f};

    f32x4 pre[3][4];   // ring: [phase][kc*2 + half], 48 VGPR

    auto load_step = [&](int s, int ph) {
        int ka = s * 64 + ksl;
        int kb = ka + 32;
        if (ka >= FLATK) ka -= FLATK;   // pad-k lanes: safe in-row garbage, B=0 there
        if (kb >= FLATK) kb -= FLATK;
        pre[ph][0] = *(const f32x4*)(xr + ka);
        pre[ph][1] = *(const f32x4*)(xr + ka + 4);
        pre[ph][2] = *(const f32x4*)(xr + kb);
        pre[ph][3] = *(const f32x4*)(xr + kb + 4);
    };

    auto compute = [&](int s, int ph) {
        #pragma unroll
        for (int kc = 0; kc < 2; ++kc) {
            union { u32x4 u; bfrag b; } a;
            const f32x4 lo = pre[ph][2 * kc];
            const f32x4 hi = pre[ph][2 * kc + 1];
            asm("v_cvt_pk_bf16_f32 %0, %1, %2" : "=v"(a.u.x) : "v"(lo.x), "v"(lo.y));
            asm("v_cvt_pk_bf16_f32 %0, %1, %2" : "=v"(a.u.y) : "v"(lo.z), "v"(lo.w));
            asm("v_cvt_pk_bf16_f32 %0, %1, %2" : "=v"(a.u.z) : "v"(hi.x), "v"(hi.y));
            asm("v_cvt_pk_bf16_f32 %0, %1, %2" : "=v"(a.u.w) : "v"(hi.z), "v"(hi.w));
            const int kb = s * 64 + (kc << 5) + ksl;
            #pragma unroll
            for (int nt = 0; nt < 8; ++nt) {
                const bfrag bw = *(const bfrag*)(w1b + (size_t)((nt << 4) + (lane & 15)) * KP + kb);
                acc[nt] = __builtin_amdgcn_mfma_f32_16x16x32_bf16(a.b, bw, acc[nt], 0, 0, 0);
            }
        }
    };

    load_step(0, 0);
    load_step(1, 1);
    #pragma unroll
    for (int s = 0; s < NSTEPS; ++s) {
        if (s + 2 < NSTEPS) load_step(s + 2, (s + 2) % 3);
        compute(s, s % 3);
    }

    // epilogue 1: bias + relu -> bf16 h1 in LDS (transpose via LDS)
    #pragma unroll
    for (int nt = 0; nt < 8; ++nt) {
        int col = (nt << 4) + (lane & 15);
        float bias = (col < HID) ? b1[col] : 0.f;
        int rbase = (wv << 4) + ((lane >> 4) << 2);
        #pragma unroll
        for (int q = 0; q < 4; ++q) {
            float v = acc[nt][q] + bias;
            H1[rbase + q][col] = f2bf(fmaxf(v, 0.f));
        }
    }
    __syncthreads();

    // layer 2: 16 rows/wave x 16 cols over K=128 (pad cols/k are exact zeros)
    f32x4 acc2 = f32x4{0.f, 0.f, 0.f, 0.f};
    #pragma unroll
    for (int ks = 0; ks < 4; ++ks) {
        const bfrag bw = *(const bfrag*)(w2b + (lane & 15) * 128 + (ks << 5) + ksl);
        const bfrag ah = *(const bfrag*)&H1[(wv << 4) + (lane & 15)][(ks << 5) + ksl];
        acc2 = __builtin_amdgcn_mfma_f32_16x16x32_bf16(ah, bw, acc2, 0, 0, 0);
    }

    int col = lane & 15;
    if (col < NCLS) {
        float bias2 = b2[col];
        int rbase = row0 + (wv << 4) + ((lane >> 4) << 2);
        #pragma unroll
        for (int q = 0; q < 4; ++q)
            out[(size_t)(rbase + q) * NCLS + col] = acc2[q] + bias2;
    }
}

extern "C" void kernel_launch(void* const* d_in, const int* in_sizes, int n_in,
                              void* d_out, int out_size, void* d_ws, size_t ws_size,
                              hipStream_t stream) {
    const float* x      = (const float*)d_in[0];
    const float* conv_w = (const float*)d_in[1];
    const float* w1     = (const float*)d_in[2];
    const float* b1     = (const float*)d_in[3];
    const float* w2     = (const float*)d_in[4];
    const float* b2     = (const float*)d_in[5];
    float* out = (float*)d_out;

    unsigned short* w1b = (unsigned short*)d_ws;   // 128*832*2 = 208 KB
    unsigned short* w2b = w1b + 128 * KP;          // 16*128*2  = 4 KB

    build_weights<<<(128 * KP + 16 * 128 + 255) / 256, 256, 0, stream>>>(conv_w, w1, w2, w1b, w2b);
    fused_fwd<<<65536 / BM, 256, 0, stream>>>(x, w1b, b1, w2b, b2, out);
}

// Round 7
// 73.661 us; speedup vs baseline: 1.5740x; 1.5740x over previous
//
#include <hip/hip_runtime.h>

#define IMG 28
#define FLATK 784     // 28*28
#define OHW 26
#define FLAT 676      // 26*26
#define HID 100
#define NCLS 10
#define KP 800        // K padded to 25*32
#define NSTEPS 25     // K-steps of 32
#define BM 64         // rows per block (4 waves x 16 rows)
#define ABUF 8192     // one A buffer: 64 rows x 32 f32

typedef __attribute__((ext_vector_type(8))) short bfrag;   // 8 bf16 (4 VGPR)
typedef __attribute__((ext_vector_type(4))) float f32x4;
typedef __attribute__((ext_vector_type(4))) unsigned int u32x4;

__device__ __forceinline__ unsigned short f2bf(float f) {
    unsigned u = __float_as_uint(f);
    u = (u + 0x7fffu + ((u >> 16) & 1u)) >> 16;   // RNE
    return (unsigned short)u;
}

// Kernel 1: fold conv into fc1 -> bf16 W1eff [128 n][800 k] (zero-padded),
// and w2 -> bf16 [16 n][128 k] (zero-padded).
__global__ void build_weights(const float* __restrict__ conv_w,
                              const float* __restrict__ w1,
                              const float* __restrict__ w2,
                              unsigned short* __restrict__ w1b,
                              unsigned short* __restrict__ w2b) {
    int idx = blockIdx.x * blockDim.x + threadIdx.x;
    if (idx < 128 * KP) {
        int n = idx / KP, k = idx - n * KP;
        float val = 0.f;
        if (n < HID && k < FLATK) {
            int qr = k / IMG, qc = k % IMG;
            #pragma unroll
            for (int i = 0; i < 3; ++i) {
                int r = qr - i;
                if (r < 0 || r >= OHW) continue;
                #pragma unroll
                for (int j = 0; j < 3; ++j) {
                    int c = qc - j;
                    if (c < 0 || c >= OHW) continue;
                    val += conv_w[i * 3 + j] * w1[n * FLAT + r * OHW + c];
                }
            }
        }
        w1b[idx] = f2bf(val);
    } else {
        int t = idx - 128 * KP;
        if (t < 16 * 128) {
            int n = t >> 7, k = t & 127;
            float v = (n < NCLS && k < HID) ? w2[n * HID + k] : 0.f;
            w2b[t] = f2bf(v);
        }
    }
}

// Kernel 2: R2-verbatim structure (staging lambda, offset=0 global_load_lds,
// explicit vmcnt(0)+__syncthreads per step, B direct from L2-hot w1b).
// Changes vs R2: BM 128->64 (grid 1024 -> 4 blocks/CU, 16 waves/CU) and
// cvt_pk bf16 conversion (R3/R4-proven) instead of scalar f2bf.
__global__ __launch_bounds__(256, 4) void fused_fwd(
    const float* __restrict__ x,              // [65536][784] f32
    const unsigned short* __restrict__ w1b,   // [128][800] bf16
    const float* __restrict__ b1,             // [100]
    const unsigned short* __restrict__ w2b,   // [16][128] bf16
    const float* __restrict__ b2,             // [10]
    float* __restrict__ out)                  // [65536][10] f32
{
    // main loop: 2 A-buffers (16384 B); epilogue: h1 [64][136] bf16 (17408 B)
    __shared__ char smem[17408] __attribute__((aligned(128)));

    const int tid  = threadIdx.x;
    const int lane = tid & 63;
    const int wv   = tid >> 6;       // 0..3
    const int r15  = lane & 15;
    const int khi  = lane >> 4;      // 0..3 (k-slice *8)
    const int row0 = blockIdx.x * BM;

    // stage geometry (R2-verified): thread covers 2 chunks of 8 rows x 32 f32;
    // source col pre-swizzled so linear LDS dest equals swizzled layout
    const int lrow = lane >> 3;                 // 0..7
    const int cfl  = ((lane & 7) ^ lrow) << 2;  // source col (floats)

    f32x4 acc[8];
    #pragma unroll
    for (int n = 0; n < 8; ++n) acc[n] = f32x4{0.f, 0.f, 0.f, 0.f};

    auto stage = [&](int s, unsigned bufoff) {
        #pragma unroll
        for (int c = 0; c < 2; ++c) {
            int chunk = (wv << 1) + c;          // 0..7
            int row = (chunk << 3) + lrow;
            int col = (s << 5) + cfl;
            if (col >= FLATK) col -= FLATK;     // pad lanes: in-row garbage, B=0 there
            const float* g = x + (size_t)(row0 + row) * FLATK + col;
            __builtin_amdgcn_global_load_lds(
                (const __attribute__((address_space(1))) void*)g,
                (__attribute__((address_space(3))) void*)(smem + bufoff + chunk * 1024),
                16, 0, 0);
        }
    };

    auto compute = [&](int s, unsigned bufoff) {
        const int k0 = s << 5;
        // A fragment: lane holds row (lane&15) of the wave's 16-row slab,
        // k-slice khi*8 .. +8; read swizzled, convert with cvt_pk
        const unsigned alog = (unsigned)(((wv << 4) + r15) * 128 + (khi << 5));
        const unsigned swz  = (unsigned)((r15 & 7) << 4);
        f32x4 lo = *(const f32x4*)(smem + bufoff + (alog ^ swz));
        f32x4 hi = *(const f32x4*)(smem + bufoff + ((alog + 16u) ^ swz));
        union { u32x4 u; bfrag b; } a;
        asm("v_cvt_pk_bf16_f32 %0, %1, %2" : "=v"(a.u.x) : "v"(lo.x), "v"(lo.y));
        asm("v_cvt_pk_bf16_f32 %0, %1, %2" : "=v"(a.u.y) : "v"(lo.z), "v"(lo.w));
        asm("v_cvt_pk_bf16_f32 %0, %1, %2" : "=v"(a.u.z) : "v"(hi.x), "v"(hi.y));
        asm("v_cvt_pk_bf16_f32 %0, %1, %2" : "=v"(a.u.w) : "v"(hi.z), "v"(hi.w));
        #pragma unroll
        for (int nt = 0; nt < 8; ++nt) {
            const bfrag bw = *(const bfrag*)(w1b + (size_t)((nt << 4) + r15) * KP
                                             + k0 + (khi << 3));
            acc[nt] = __builtin_amdgcn_mfma_f32_16x16x32_bf16(a.b, bw, acc[nt], 0, 0, 0);
        }
    };

    stage(0, 0u);
    #pragma unroll 2
    for (int s = 0; s < NSTEPS; ++s) {
        unsigned cur = (s & 1) ? (unsigned)ABUF : 0u;
        asm volatile("s_waitcnt vmcnt(0)" ::: "memory");  // own staging DMA done
        __syncthreads();                                   // everyone's staging done
        if (s + 1 < NSTEPS) stage(s + 1, cur ^ ABUF);
        compute(s, cur);
    }
    __syncthreads();   // all A reads done before aliasing smem with h1

    // epilogue 1: bias + relu -> bf16 h1 in LDS [64][136]
    unsigned short (*H1)[136] = (unsigned short (*)[136])smem;
    #pragma unroll
    for (int nt = 0; nt < 8; ++nt) {
        int col = (nt << 4) + r15;
        float bias = (col < HID) ? b1[col] : 0.f;
        int rb = (wv << 4) + (khi << 2);
        #pragma unroll
        for (int q = 0; q < 4; ++q) {
            float v = acc[nt][q] + bias;
            H1[rb + q][col] = f2bf(fmaxf(v, 0.f));
        }
    }
    __syncthreads();

    // layer 2: wave wv handles rows [wv*16, wv*16+16), K=128 (pads are zeros)
    f32x4 acc2 = f32x4{0.f, 0.f, 0.f, 0.f};
    const int r2 = (wv << 4) + r15;
    #pragma unroll
    for (int ks = 0; ks < 4; ++ks) {
        const bfrag ah = *(const bfrag*)&H1[r2][(ks << 5) + (khi << 3)];
        const bfrag bw = *(const bfrag*)(w2b + r15 * 128 + (ks << 5) + (khi << 3));
        acc2 = __builtin_amdgcn_mfma_f32_16x16x32_bf16(ah, bw, acc2, 0, 0, 0);
    }
    if (r15 < NCLS) {
        float b2v = b2[r15];
        int rb = row0 + (wv << 4) + (khi << 2);
        #pragma unroll
        for (int q = 0; q < 4; ++q)
            out[(size_t)(rb + q) * NCLS + r15] = acc2[q] + b2v;
    }
}

extern "C" void kernel_launch(void* const* d_in, const int* in_sizes, int n_in,
                              void* d_out, int out_size, void* d_ws, size_t ws_size,
                              hipStream_t stream) {
    const float* x      = (const float*)d_in[0];
    const float* conv_w = (const float*)d_in[1];
    const float* w1     = (const float*)d_in[2];
    const float* b1     = (const float*)d_in[3];
    const float* w2     = (const float*)d_in[4];
    const float* b2     = (const float*)d_in[5];
    float* out = (float*)d_out;

    unsigned short* w1b = (unsigned short*)d_ws;   // 128*800*2 = 204.8 KB
    unsigned short* w2b = w1b + 128 * KP;          // 16*128*2  = 4 KB

    build_weights<<<(128 * KP + 16 * 128 + 255) / 256, 256, 0, stream>>>(conv_w, w1, w2, w1b, w2b);
    fused_fwd<<<65536 / BM, 256, 0, stream>>>(x, w1b, b1, w2b, b2, out);
}

// Round 8
// 64.474 us; speedup vs baseline: 1.7983x; 1.1425x over previous
//
#include <hip/hip_runtime.h>

#define IMG 28
#define FLATK 784     // 28*28
#define OHW 26
#define FLAT 676      // 26*26
#define HID 100
#define NCLS 10
#define KP 800        // K padded to 25*32
#define NSTEPS 25     // K-steps of 32
#define BM 128        // rows per block (4 waves x 32 rows)

typedef __attribute__((ext_vector_type(8))) short bfrag;   // 8 bf16 (4 VGPR)
typedef __attribute__((ext_vector_type(4))) float f32x4;
typedef __attribute__((ext_vector_type(4))) unsigned int u32x4;

__device__ __forceinline__ unsigned short f2bf(float f) {
    unsigned u = __float_as_uint(f);
    u = (u + 0x7fffu + ((u >> 16) & 1u)) >> 16;   // RNE
    return (unsigned short)u;
}

// Kernel 1: fold conv into fc1 -> bf16 W1eff [128 n][800 k] (zero-padded),
// and w2 -> bf16 [16 n][128 k] (zero-padded).
__global__ void build_weights(const float* __restrict__ conv_w,
                              const float* __restrict__ w1,
                              const float* __restrict__ w2,
                              unsigned short* __restrict__ w1b,
                              unsigned short* __restrict__ w2b) {
    int idx = blockIdx.x * blockDim.x + threadIdx.x;
    if (idx < 128 * KP) {
        int n = idx / KP, k = idx - n * KP;
        float val = 0.f;
        if (n < HID && k < FLATK) {
            int qr = k / IMG, qc = k % IMG;
            #pragma unroll
            for (int i = 0; i < 3; ++i) {
                int r = qr - i;
                if (r < 0 || r >= OHW) continue;
                #pragma unroll
                for (int j = 0; j < 3; ++j) {
                    int c = qc - j;
                    if (c < 0 || c >= OHW) continue;
                    val += conv_w[i * 3 + j] * w1[n * FLAT + r * OHW + c];
                }
            }
        }
        w1b[idx] = f2bf(val);
    } else {
        int t = idx - 128 * KP;
        if (t < 16 * 128) {
            int n = t >> 7, k = t & 127;
            float v = (n < NCLS && k < HID) ? w2[n * HID + k] : 0.f;
            w2b[t] = f2bf(v);
        }
    }
}

// Kernel 2: R2-verbatim structure (BM=128, 4 waves x 32 rows, staging lambda
// with offset=0 global_load_lds, explicit vmcnt(0)+__syncthreads per step,
// B direct from L2-hot w1b). Single change vs R2: v_cvt_pk_bf16_f32 packed
// conversion (R3/R4/R7-proven) instead of 16 scalar f2bf per step.
__global__ __launch_bounds__(256) void fused_fwd(
    const float* __restrict__ x,              // [65536][784] f32
    const unsigned short* __restrict__ w1b,   // [128][800] bf16
    const float* __restrict__ b1,             // [100]
    const unsigned short* __restrict__ w2b,   // [16][128] bf16
    const float* __restrict__ b2,             // [10]
    float* __restrict__ out)                  // [65536][10] f32
{
    // A double buffer: 2 x [128 rows][32 f32] = 2 x 16 KB.
    // h1 (after main loop, aliased): [128][136] bf16 = 34816 B.
    __shared__ char smem[34816] __attribute__((aligned(128)));

    const int tid  = threadIdx.x;
    const int lane = tid & 63;
    const int wv   = tid >> 6;
    const int row0 = blockIdx.x * BM;

    // staging source geometry: dest phys = chunk*1024 + lane*16 (linear);
    // logical = phys ^ ((row&7)<<4)  =>  per-lane source col swizzle
    const int lrow = lane >> 3;                     // row within 8-row chunk
    const int cfl  = ((lane & 7) ^ lrow) * 4;       // source col (floats)

    f32x4 acc[2][8];
    #pragma unroll
    for (int m = 0; m < 2; ++m)
        #pragma unroll
        for (int n = 0; n < 8; ++n)
            acc[m][n] = f32x4{0.f, 0.f, 0.f, 0.f};

    auto stage = [&](int k0, unsigned bufoff) {
        #pragma unroll
        for (int c = 0; c < 4; ++c) {
            int chunk = (wv << 2) + c;
            int row = (chunk << 3) + lrow;
            int col = k0 + cfl;
            if (col >= FLATK) col -= FLATK;   // pad lanes: read safe garbage (B rows are 0 there)
            const float* g = x + (size_t)(row0 + row) * FLATK + col;
            __builtin_amdgcn_global_load_lds(
                (const __attribute__((address_space(1))) void*)g,
                (__attribute__((address_space(3))) void*)(smem + bufoff + chunk * 1024),
                16, 0, 0);
        }
    };

    auto compute = [&](int k0, unsigned bufoff) {
        // A fragments: lane holds row (lane&15), k = (lane>>4)*8 .. +8
        bfrag af[2];
        #pragma unroll
        for (int mf = 0; mf < 2; ++mf) {
            int r = (wv << 5) + (mf << 4) + (lane & 15);
            unsigned alog = ((unsigned)r << 7) + (unsigned)((lane >> 4) << 5);
            unsigned sw = (unsigned)((r & 7) << 4);
            f32x4 lo = *(const f32x4*)(smem + bufoff + (alog ^ sw));
            f32x4 hi = *(const f32x4*)(smem + bufoff + ((alog + 16u) ^ sw));
            union { u32x4 u; bfrag b; } a;
            asm("v_cvt_pk_bf16_f32 %0, %1, %2" : "=v"(a.u.x) : "v"(lo.x), "v"(lo.y));
            asm("v_cvt_pk_bf16_f32 %0, %1, %2" : "=v"(a.u.y) : "v"(lo.z), "v"(lo.w));
            asm("v_cvt_pk_bf16_f32 %0, %1, %2" : "=v"(a.u.z) : "v"(hi.x), "v"(hi.y));
            asm("v_cvt_pk_bf16_f32 %0, %1, %2" : "=v"(a.u.w) : "v"(hi.z), "v"(hi.w));
            af[mf] = a.b;
        }
        // B fragments straight from L2-resident w1b: lane holds col (lane&15)
        #pragma unroll
        for (int nt = 0; nt < 8; ++nt) {
            const bfrag bw = *(const bfrag*)(w1b + ((size_t)((nt << 4) + (lane & 15))) * KP
                                             + k0 + ((lane >> 4) << 3));
            acc[0][nt] = __builtin_amdgcn_mfma_f32_16x16x32_bf16(af[0], bw, acc[0][nt], 0, 0, 0);
            acc[1][nt] = __builtin_amdgcn_mfma_f32_16x16x32_bf16(af[1], bw, acc[1][nt], 0, 0, 0);
        }
    };

    stage(0, 0u);
    #pragma unroll 2
    for (int s = 0; s < NSTEPS; ++s) {
        unsigned cur = (s & 1) ? 16384u : 0u;
        asm volatile("s_waitcnt vmcnt(0)" ::: "memory");  // own staging DMA done
        __syncthreads();                                   // everyone's staging done
        if (s + 1 < NSTEPS) stage((s + 1) << 5, cur ^ 16384u);
        compute(s << 5, cur);
    }
    __syncthreads();   // all A reads done before aliasing smem with h1

    // epilogue 1: bias + relu -> bf16 h1 in LDS [128][136]
    unsigned short (*H1)[136] = (unsigned short (*)[136])smem;
    #pragma unroll
    for (int nt = 0; nt < 8; ++nt) {
        int col = (nt << 4) + (lane & 15);
        float bias = (col < HID) ? b1[col] : 0.f;
        #pragma unroll
        for (int mf = 0; mf < 2; ++mf) {
            int rbase = (wv << 5) + (mf << 4) + ((lane >> 4) << 2);
            #pragma unroll
            for (int q = 0; q < 4; ++q) {
                float v = acc[mf][nt][q] + bias;
                H1[rbase + q][col] = f2bf(fmaxf(v, 0.f));
            }
        }
    }
    __syncthreads();

    // layer 2: [128 rows] x [16 cols] over K=128 (pad cols/k are exact zeros)
    f32x4 acc2[2] = {f32x4{0.f,0.f,0.f,0.f}, f32x4{0.f,0.f,0.f,0.f}};
    #pragma unroll
    for (int ks = 0; ks < 4; ++ks) {
        const bfrag bw = *(const bfrag*)(w2b + (lane & 15) * 128 + (ks << 5) + ((lane >> 4) << 3));
        #pragma unroll
        for (int mf = 0; mf < 2; ++mf) {
            int r = (wv << 5) + (mf << 4) + (lane & 15);
            const bfrag ah = *(const bfrag*)&H1[r][(ks << 5) + ((lane >> 4) << 3)];
            acc2[mf] = __builtin_amdgcn_mfma_f32_16x16x32_bf16(ah, bw, acc2[mf], 0, 0, 0);
        }
    }

    int col = lane & 15;
    if (col < NCLS) {
        float bias2 = b2[col];
        #pragma unroll
        for (int mf = 0; mf < 2; ++mf) {
            int rbase = row0 + (wv << 5) + (mf << 4) + ((lane >> 4) << 2);
            #pragma unroll
            for (int q = 0; q < 4; ++q)
                out[(size_t)(rbase + q) * NCLS + col] = acc2[mf][q] + bias2;
        }
    }
}

extern "C" void kernel_launch(void* const* d_in, const int* in_sizes, int n_in,
                              void* d_out, int out_size, void* d_ws, size_t ws_size,
                              hipStream_t stream) {
    const float* x      = (const float*)d_in[0];
    const float* conv_w = (const float*)d_in[1];
    const float* w1     = (const float*)d_in[2];
    const float* b1     = (const float*)d_in[3];
    const float* w2     = (const float*)d_in[4];
    const float* b2     = (const float*)d_in[5];
    float* out = (float*)d_out;

    unsigned short* w1b = (unsigned short*)d_ws;               // 128*800*2 = 204.8 KB
    unsigned short* w2b = w1b + 128 * KP;                      // 16*128*2  = 4 KB

    build_weights<<<(128 * KP + 16 * 128 + 255) / 256, 256, 0, stream>>>(conv_w, w1, w2, w1b, w2b);
    fused_fwd<<<65536 / BM, 256, 0, stream>>>(x, w1b, b1, w2b, b2, out);
}